// Round 10
// baseline (454.018 us; speedup 1.0000x reference)
//
#include <hip/hip_runtime.h>
#include <stdint.h>

typedef __attribute__((ext_vector_type(8))) short short8;
typedef __attribute__((ext_vector_type(4))) float f32x4;

constexpr int T_ = 4;
constexpr int BNTOT = 32768; // B*N

// f32 -> bf16 (RNE)
__device__ __forceinline__ uint32_t bf1(float f) {
    uint32_t x = __builtin_bit_cast(uint32_t, f);
    return (x + 0x7FFFu + ((x >> 16) & 1u)) >> 16;
}
__device__ __forceinline__ uint32_t pk(float lo, float hi) {
    return bf1(lo) | (bf1(hi) << 16);
}

// 8 u8 {0,1} -> 8 bf16 {0,1.0}: v_perm spreads bytes to u16 lanes, *0x3F80.
__device__ __forceinline__ short8 expand8(uint2 r) {
    uint4 o;
    o.x = __builtin_amdgcn_perm(0u, r.x, 0x0C010C00u) * 0x3F80u;
    o.y = __builtin_amdgcn_perm(0u, r.x, 0x0C030C02u) * 0x3F80u;
    o.z = __builtin_amdgcn_perm(0u, r.y, 0x0C010C00u) * 0x3F80u;
    o.w = __builtin_amdgcn_perm(0u, r.y, 0x0C030C02u) * 0x3F80u;
    return __builtin_bit_cast(short8, o);
}

// x [T*BN][256] f32 -> MFMA-fragment-tiled bf16 [T*BN/16][32][16][8]
__global__ __launch_bounds__(256)
void cvt_tiled(const float* __restrict__ in, ushort* __restrict__ out) {
    const int g  = blockIdx.x * 256 + threadIdx.x;
    const int kg = g & 31;
    const int r  = (g >> 5) & 15;
    const int bt = g >> 9;
    const float* src = in + ((size_t)(bt * 16 + r)) * 256 + kg * 8;
    const float4 a = *(const float4*)src;
    const float4 b = *(const float4*)(src + 4);
    uint4 o;
    o.x = pk(a.x, a.y); o.y = pk(a.z, a.w);
    o.z = pk(b.x, b.y); o.w = pk(b.z, b.w);
    *(uint4*)(out + ((size_t)(bt * 32 + kg)) * 128 + r * 8) = o;
}

// Fused bf16-MFMA GEMM (C = A @ W^T) + multi-step LIF over T=4.
// A: MODE 0: tiled bf16 [T][BN/16][K/8][16][8]; MODE 1/2: tiled u8 (same geom).
// W: f32 [NOUT][K], staged ONCE per block to LDS (full-K panel, XOR-swizzled).
// Out: MODE 0/1: tiled u8 [T][BN/16][NOUT/8][16][8] (coalesced uint4 stores);
//      MODE 2: f32 [T][BN][NOUT] (float4 stores via LDS repack).
// Block: 4 waves; wave w owns rows [row0+16w,+16) for ALL t (thread-local
// t-scan). K-loop barrier-free.
// A-prefetch: depth-4 software pipeline with NAMED register sets aA..aD —
// NO dynamic register indexing (r9 lesson: a[s%D] -> scratch, VGPR stuck @88).
template <int MODE, int K, int NOUT>
__global__ __launch_bounds__(256, 2)
void lif_mfma(const void* __restrict__ Av,
              const float* __restrict__ W,
              void* __restrict__ Out)
{
    constexpr int NS = K / 32;      // K-steps
    constexpr int KG = K / 8;       // k-granules
    constexpr int NCOLT = NOUT / 64;
    __shared__ __align__(16) char smem[NS * 4096]; // B panel; epilogue aliases

    const int tid = threadIdx.x;
    const int l   = tid & 63;
    const int w   = tid >> 6;

    // XCD-bijective swizzle: xcd owns contiguous row-tile chunk, cols fastest.
    const int id  = blockIdx.x;
    const int xcd = id & 7;
    const int j_  = id >> 3;
    const int row0 = (xcd * 64 + j_ / NCOLT) * 64;
    const int col0 = (j_ % NCOLT) * 64;

    // ---- stage B col-panel (64 x K) f32 -> bf16 frag-tiled, XOR-swizzled ----
    // lane mapping spreads 16 COLUMNS across a quarter-wave so the ds_write
    // hits the same 2-way-floor bank pattern as the fragment reads
    // (r9's col-per-wave mapping was a 16-way write conflict).
    {
        constexpr int ITERS = 64 * KG / 256;
#pragma unroll
        for (int i = 0; i < ITERS; ++i) {
            const int idx = i * 256 + tid;
            const int c16 = idx & 15;
            const int kg  = (idx >> 4) & (KG - 1);
            const int chi = idx / (16 * KG);
            const float* wp = W + (size_t)(col0 + chi * 16 + c16) * K + kg * 8;
            const float4 f0 = *(const float4*)wp;
            const float4 f1 = *(const float4*)(wp + 4);
            uint4 o;
            o.x = pk(f0.x, f0.y); o.y = pk(f0.z, f0.w);
            o.z = pk(f1.x, f1.y); o.w = pk(f1.z, f1.w);
            *(uint4*)(smem + (chi * NS + (kg >> 2)) * 1024 + c16 * 64 +
                      (((kg & 3) ^ ((c16 >> 1) & 3)) * 16)) = o;
        }
    }
    __syncthreads();

    const char* bbase = smem + (l & 15) * 64 + (((l >> 4) ^ ((l >> 1) & 3)) * 16);
    const int rb = (row0 >> 4) + w;

    f32x4 acc[T_][4];
#pragma unroll
    for (int t = 0; t < T_; ++t)
#pragma unroll
        for (int n = 0; n < 4; ++n) acc[t][n] = (f32x4)0.f;

    size_t aunit[T_];
#pragma unroll
    for (int t = 0; t < T_; ++t)
        aunit[t] = ((size_t)(t * (BNTOT / 16) + rb)) * KG + (l >> 4);

    auto loadAb = [&](int s, short8* a) {
#pragma unroll
        for (int t = 0; t < T_; ++t)
            a[t] = *(const short8*)((const ushort*)Av +
                     (aunit[t] + s * 4) * 128 + (l & 15) * 8);
    };
    auto loadAu = [&](int s, uint2* a) {
#pragma unroll
        for (int t = 0; t < T_; ++t)
            a[t] = *(const uint2*)((const uint8_t*)Av +
                     (aunit[t] + s * 4) * 128 + (l & 15) * 8);
    };
    auto stepB = [&](const short8* a, int s) {
        short8 bfr[4];
#pragma unroll
        for (int n = 0; n < 4; ++n)
            bfr[n] = *(const short8*)(bbase + (n * NS + s) * 1024);
#pragma unroll
        for (int t = 0; t < T_; ++t)
#pragma unroll
            for (int n = 0; n < 4; ++n)
                acc[t][n] = __builtin_amdgcn_mfma_f32_16x16x32_bf16(
                    a[t], bfr[n], acc[t][n], 0, 0, 0);
    };
    auto stepU = [&](const uint2* a, int s) {
        short8 bfr[4];
#pragma unroll
        for (int n = 0; n < 4; ++n)
            bfr[n] = *(const short8*)(bbase + (n * NS + s) * 1024);
#pragma unroll
        for (int t = 0; t < T_; ++t) {
            const short8 af = expand8(a[t]);
#pragma unroll
            for (int n = 0; n < 4; ++n)
                acc[t][n] = __builtin_amdgcn_mfma_f32_16x16x32_bf16(
                    af, bfr[n], acc[t][n], 0, 0, 0);
        }
    };

    // ---- barrier-free K-loop: depth-4 pipeline, NAMED sets, static regs ----
    if constexpr (MODE == 0) {
        short8 aA[T_], aB[T_], aC[T_], aD[T_];
        loadAb(0, aA); loadAb(1, aB); loadAb(2, aC); loadAb(3, aD);
        for (int sb = 0; sb + 4 < NS; sb += 4) {
            stepB(aA, sb + 0); loadAb(sb + 4, aA);
            stepB(aB, sb + 1); loadAb(sb + 5, aB);
            stepB(aC, sb + 2); loadAb(sb + 6, aC);
            stepB(aD, sb + 3); loadAb(sb + 7, aD);
        }
        stepB(aA, NS - 4); stepB(aB, NS - 3);
        stepB(aC, NS - 2); stepB(aD, NS - 1);
    } else {
        uint2 aA[T_], aB[T_], aC[T_], aD[T_];
        loadAu(0, aA); loadAu(1, aB); loadAu(2, aC); loadAu(3, aD);
        for (int sb = 0; sb + 4 < NS; sb += 4) {
            stepU(aA, sb + 0); loadAu(sb + 4, aA);
            stepU(aB, sb + 1); loadAu(sb + 5, aB);
            stepU(aC, sb + 2); loadAu(sb + 6, aC);
            stepU(aD, sb + 3); loadAu(sb + 7, aD);
        }
        stepU(aA, NS - 4); stepU(aB, NS - 3);
        stepU(aC, NS - 2); stepU(aD, NS - 1);
    }

    __syncthreads();   // B panel dead; epilogue LDS aliases it

    // ---- epilogue: thread-local LIF t-scan + LDS repack + coalesced stores ----
    // C/D map: col = l&15 (+n*16), row = (l>>4)*4 + j (+ w*16)
    if constexpr (MODE == 2) {
        float* fl = (float*)smem;              // [64][68] f32, padded
        float v[4][4];
#pragma unroll
        for (int n = 0; n < 4; ++n)
#pragma unroll
            for (int j = 0; j < 4; ++j) v[n][j] = 0.f;
#pragma unroll
        for (int t = 0; t < T_; ++t) {
#pragma unroll
            for (int n = 0; n < 4; ++n)
#pragma unroll
                for (int j = 0; j < 4; ++j) {
                    v[n][j] = 0.5f * (v[n][j] + acc[t][n][j]);
                    const bool sp = (v[n][j] >= 1.f);
                    if (sp) v[n][j] = 0.f;
                    fl[(w * 16 + (l >> 4) * 4 + j) * 68 + n * 16 + (l & 15)] =
                        sp ? 1.f : 0.f;
                }
            __syncthreads();
            const int r  = tid >> 2;
            const int cb = (tid & 3) * 16;
            float* op = (float*)Out +
                ((size_t)(t * BNTOT + row0 + r)) * NOUT + col0 + cb;
#pragma unroll
            for (int k = 0; k < 4; ++k)
                *(float4*)(op + k * 4) = *(const float4*)&fl[r * 68 + cb + k * 4];
            __syncthreads();
        }
    } else {
        char* el = smem;   // [4t][4w][8cg][16r][8c] = 16KB
        float v[4][4];
#pragma unroll
        for (int n = 0; n < 4; ++n)
#pragma unroll
            for (int j = 0; j < 4; ++j) v[n][j] = 0.f;
#pragma unroll
        for (int t = 0; t < T_; ++t)
#pragma unroll
            for (int n = 0; n < 4; ++n)
#pragma unroll
                for (int j = 0; j < 4; ++j) {
                    v[n][j] = 0.5f * (v[n][j] + acc[t][n][j]);
                    const bool sp = (v[n][j] >= 1.f);
                    if (sp) v[n][j] = 0.f;
                    el[t * 4096 + w * 1024 + (n * 2 + ((l & 15) >> 3)) * 128 +
                       ((l >> 4) * 4 + j) * 8 + (l & 7)] =
                        (MODE == 0) ? (sp ? 1 : 0) : (sp ? 0 : 0xFF);
                }
        __syncthreads();
        // 64 consecutive bytes per thread -> 4 coalesced uint4 stores
        const int lin = tid * 64;
        const int t  = lin >> 12;
        const int w2 = (lin >> 10) & 3;
        const int cg = (lin >> 7) & 7;
        const size_t gb = ((size_t)(t * (BNTOT / 16) + (row0 >> 4) + w2) *
                          (NOUT / 8) + (col0 >> 3) + cg) * 128 + (lin & 127);
#pragma unroll
        for (int k = 0; k < 4; ++k) {
            uint4 m = *(const uint4*)(el + lin + k * 16);
            if constexpr (MODE == 1) {
                const uint4 h = *(const uint4*)((const uint8_t*)Av + gb + k * 16);
                m.x &= h.x; m.y &= h.y; m.z &= h.z; m.w &= h.w;
            }
            *(uint4*)((uint8_t*)Out + gb + k * 16) = m;
        }
    }
}

extern "C" void kernel_launch(void* const* d_in, const int* in_sizes, int n_in,
                              void* d_out, int out_size, void* d_ws, size_t ws_size,
                              hipStream_t stream)
{
    const float* x     = (const float*)d_in[0];  // [4,32,1024,256]
    const float* w_in  = (const float*)d_in[1];  // [512,256]
    const float* w_h   = (const float*)d_in[2];  // [2,512,512]
    const float* w_out = (const float*)d_in[3];  // [256,512]

    // xbf (tiled bf16 x, 67MB) = d_out[0:67MB] (dead before L4 writes out)
    // hA u8 = d_ws[0:67.1MB), hB u8 = d_ws[67.1:134.2MB)
    ushort*  xbf = (ushort*)d_out;
    uint8_t* hA  = (uint8_t*)d_ws;
    uint8_t* hB  = hA + (size_t)T_ * BNTOT * 512;
    float*   out = (float*)d_out;

    cvt_tiled<<<16384, 256, 0, stream>>>(x, xbf);

    lif_mfma<0, 256, 512><<<4096, 256, 0, stream>>>(xbf, w_in, hA);
    lif_mfma<1, 512, 512><<<4096, 256, 0, stream>>>(hA, w_h, hB);
    lif_mfma<1, 512, 512><<<4096, 256, 0, stream>>>(hB, w_h + 512 * 512, hA);
    lif_mfma<2, 512, 256><<<2048, 256, 0, stream>>>(hA, w_out, out);
}